// Round 1
// 308.543 us; speedup vs baseline: 1.0160x; 1.0160x over previous
//
#include <hip/hip_runtime.h>
#include <math.h>

#define S_TOK 8192
#define M_DIM 4096
#define NEXP 64
#define CAPACITY 256   // K * ceil(S/E) = 2*128
#define NCHUNK 128     // S / 64
#define KS 16          // split-K slices
#define KSL 256        // slice length (KS*KSL = M_DIM)
#define BT 256         // tokens per tile
#define BK 32          // k per LDS chunk
#define NC (KSL / BK)  // 8 chunks per slice

// ---------------------------------------------------------------------------
// K1: partial logits, split-K. Grid 512 = 32 token-tiles x 16 k-slices.
// 8tok x 8exp register tile (1 B LDS per FMA -> VALU-bound, not LDS-bound);
// XOR-quad-swizzled k-major LDS (<=2-way conflicts on store and read).
// LDS: 2*(32KB x) + 2*(8KB wg) = 80 KB -> 2 blocks/CU.
// ---------------------------------------------------------------------------
__global__ __launch_bounds__(256) void k_logits(
    const float* __restrict__ x, const float* __restrict__ wg,
    float* __restrict__ part)
{
    __shared__ float xs[2][BK * BT];   // [k][token (quad-swizzled)]
    __shared__ float wsl[2][BK * 64];  // [k][expert (quad-swizzled)]
    const int tid = threadIdx.x;
    const int tile = blockIdx.x >> 4;      // 0..31
    const int ks   = blockIdx.x & 15;      // 0..15
    const int t0 = tile * BT;
    const int kb = ks * KSL;

    const int tx = tid & 7;                // experts 8*tx..8*tx+7
    const int ty = tid >> 3;               // tokens  8*ty..8*ty+7

    float4 rx[8], rw[2];
    auto ld = [&](int kc) {
        #pragma unroll
        for (int i = 0; i < 8; ++i) {
            const int item = tid + 256 * i;           // 2048 items: 256 tok x 8 kq
            const int r = item >> 3, kq = item & 7;
            rx[i] = *(const float4*)(x + (size_t)(t0 + r) * M_DIM + kc + 4 * kq);
        }
        #pragma unroll
        for (int i = 0; i < 2; ++i) {
            const int item = tid + 256 * i;           // 512 items: 64 exp x 8 kq
            const int r = item >> 3, kq = item & 7;
            rw[i] = *(const float4*)(wg + (size_t)r * M_DIM + kc + 4 * kq);
        }
    };
    auto st = [&](int buf) {
        #pragma unroll
        for (int i = 0; i < 8; ++i) {
            const int item = tid + 256 * i;
            const int r = item >> 3, kq = item & 7;
            const int quad = r >> 2, lo = r & 3;
            const float v[4] = {rx[i].x, rx[i].y, rx[i].z, rx[i].w};
            #pragma unroll
            for (int j = 0; j < 4; ++j)
                xs[buf][(4 * kq + j) * BT + ((quad ^ kq) << 2) + lo] = v[j];
        }
        #pragma unroll
        for (int i = 0; i < 2; ++i) {
            const int item = tid + 256 * i;
            const int r = item >> 3, kq = item & 7;
            const int quad = r >> 2, lo = r & 3;
            const float v[4] = {rw[i].x, rw[i].y, rw[i].z, rw[i].w};
            #pragma unroll
            for (int j = 0; j < 4; ++j)
                wsl[buf][(4 * kq + j) * 64 + ((quad ^ kq) << 2) + lo] = v[j];
        }
    };

    float acc[8][8] = {};
    ld(kb);
    st(0);
    __syncthreads();
    for (int c = 0; c < NC; ++c) {
        const int buf = c & 1;
        if (c + 1 < NC) ld(kb + (c + 1) * BK);
        #pragma unroll 4
        for (int kk = 0; kk < BK; ++kk) {
            const int sw = kk >> 2;
            const float4 a0 = *(const float4*)&xs [buf][kk * BT + (((2 * ty)     ^ sw) << 2)];
            const float4 a1 = *(const float4*)&xs [buf][kk * BT + (((2 * ty + 1) ^ sw) << 2)];
            const float4 b0 = *(const float4*)&wsl[buf][kk * 64 + (((2 * tx)     ^ sw) << 2)];
            const float4 b1 = *(const float4*)&wsl[buf][kk * 64 + (((2 * tx + 1) ^ sw) << 2)];
            const float av[8] = {a0.x, a0.y, a0.z, a0.w, a1.x, a1.y, a1.z, a1.w};
            const float bv[8] = {b0.x, b0.y, b0.z, b0.w, b1.x, b1.y, b1.z, b1.w};
            #pragma unroll
            for (int i = 0; i < 8; ++i)
                #pragma unroll
                for (int j = 0; j < 8; ++j)
                    acc[i][j] = fmaf(av[i], bv[j], acc[i][j]);
        }
        __syncthreads();
        if (c + 1 < NC) st(buf ^ 1);
        __syncthreads();
    }

    #pragma unroll
    for (int i = 0; i < 8; ++i) {
        float4 v0, v1;
        v0.x = acc[i][0]; v0.y = acc[i][1]; v0.z = acc[i][2]; v0.w = acc[i][3];
        v1.x = acc[i][4]; v1.y = acc[i][5]; v1.z = acc[i][6]; v1.w = acc[i][7];
        float* dst = part + ((size_t)ks * S_TOK + t0 + 8 * ty + i) * NEXP + 8 * tx;
        *(float4*)dst = v0;
        *(float4*)(dst + 4) = v1;
    }
}

// ---------------------------------------------------------------------------
// K2 (fused reduce+rank): 64 tokens per block (8 waves x 8 tokens).
// Reduce partials (deterministic slice order) + softmax + top-2 + me,
// then wave 0 does the per-chunk in-order ranks/histograms via ballots.
// ---------------------------------------------------------------------------
__global__ __launch_bounds__(512) void k_gate(
    const float* __restrict__ part, float* __restrict__ me_g,
    int* __restrict__ idx0_g, int* __restrict__ idx1_g,
    float* __restrict__ gn0_g, float* __restrict__ gn1_g,
    int* __restrict__ rank0_g, int* __restrict__ rank1_g,
    int* __restrict__ cnt_g /* [2][NCHUNK][64] */)
{
    __shared__ float me_sh[NEXP];
    __shared__ int e0_sh[64], e1_sh[64];
    const int tid = threadIdx.x;
    if (tid < NEXP) me_sh[tid] = 0.f;
    __syncthreads();

    const int wv = tid >> 6, lane = tid & 63;
    const int chunk = blockIdx.x;
    float me_acc = 0.f;
    for (int i = 0; i < 8; ++i) {
        const int tt = wv * 8 + i;
        const int t = chunk * 64 + tt;
        float lg = 0.f;
        #pragma unroll
        for (int s = 0; s < KS; ++s)
            lg += part[((size_t)s * S_TOK + t) * NEXP + lane];

        // argmax (lowest index on tie, matching lax.top_k)
        float v = lg; int id = lane;
        #pragma unroll
        for (int off = 32; off > 0; off >>= 1) {
            float v2 = __shfl_xor(v, off);
            int   i2 = __shfl_xor(id, off);
            if (v2 > v || (v2 == v && i2 < id)) { v = v2; id = i2; }
        }
        const float mx = v; const int i0 = id;

        const float p = expf(lg - mx);
        float sum = p;
        #pragma unroll
        for (int off = 32; off > 0; off >>= 1) sum += __shfl_xor(sum, off);
        me_acc += p / sum;

        // second argmax, excluding i0
        float v1 = (lane == i0) ? -INFINITY : lg; int id1 = lane;
        #pragma unroll
        for (int off = 32; off > 0; off >>= 1) {
            float v2 = __shfl_xor(v1, off);
            int   i2 = __shfl_xor(id1, off);
            if (v2 > v1 || (v2 == v1 && i2 < id1)) { v1 = v2; id1 = i2; }
        }

        const float g0 = 1.0f / sum;
        const float g1 = expf(v1 - mx) / sum;
        const float den = fmaxf(g0 + g1, 1.1920929e-07f);
        if (lane == 0) {
            idx0_g[t] = i0;
            idx1_g[t] = id1;
            gn0_g[t] = g0 / den;
            gn1_g[t] = g1 / den;
            e0_sh[tt] = i0;
            e1_sh[tt] = id1;
        }
    }
    atomicAdd(&me_sh[lane], me_acc);
    __syncthreads();
    if (tid < NEXP) atomicAdd(&me_g[tid], me_sh[tid]);

    // rank phase: wave 0, lane = token within chunk
    if (wv == 0) {
        const int s = chunk * 64 + lane;
        const int e0 = e0_sh[lane], e1 = e1_sh[lane];
        const unsigned long long lt = (1ull << lane) - 1ull;
        int r0 = 0, r1 = 0, c0 = 0, c1 = 0;
        #pragma unroll
        for (int e = 0; e < 64; ++e) {
            unsigned long long m0 = __ballot(e0 == e);
            unsigned long long m1 = __ballot(e1 == e);
            if (e0 == e) r0 = __popcll(m0 & lt);
            if (e1 == e) r1 = __popcll(m1 & lt);
            if (lane == e) { c0 = __popcll(m0); c1 = __popcll(m1); }
        }
        rank0_g[s] = r0;
        rank1_g[s] = r1;
        cnt_g[chunk * 64 + lane] = c0;
        cnt_g[NCHUNK * 64 + chunk * 64 + lane] = c1;
    }
}

// ---------------------------------------------------------------------------
// K3: parallel scan — one wave per (k,e), shfl prefix over 128 chunks.
// Also emits ce (tot0) and the load-balance loss.
// ---------------------------------------------------------------------------
__global__ __launch_bounds__(256) void k_scan(
    const int* __restrict__ cnt_g, int* __restrict__ base_g,
    int* __restrict__ tot0_g, const float* __restrict__ me_g,
    float* __restrict__ loss_out)
{
    const int wv = threadIdx.x >> 6, lane = threadIdx.x & 63;
    const int g = blockIdx.x * 4 + wv;         // 0..127
    const int k = g >> 6, e = g & 63;

    const int c0 = cnt_g[(k * NCHUNK + 2 * lane)     * 64 + e];
    const int c1 = cnt_g[(k * NCHUNK + 2 * lane + 1) * 64 + e];
    const int s = c0 + c1;
    int incl = s;
    #pragma unroll
    for (int d = 1; d < 64; d <<= 1) {
        int v = __shfl_up(incl, d);
        if (lane >= d) incl += v;
    }
    const int excl = incl - s;
    base_g[(k * NCHUNK + 2 * lane)     * 64 + e] = excl;
    base_g[(k * NCHUNK + 2 * lane + 1) * 64 + e] = excl + c0;
    const int total = __shfl(incl, 63);
    if (k == 0 && lane == 0) {
        tot0_g[e] = total;
        atomicAdd(loss_out, me_g[e] * (float)total * 9.5367431640625e-07f); // E/S^2
    }
}

// ---------------------------------------------------------------------------
// K4 (fused weight+out): per-token combine weight (capacity check) computed
// block-uniformly (L1 broadcast loads), then out[s,:] = w * x[s,:].
// ---------------------------------------------------------------------------
__global__ __launch_bounds__(256) void k_out(
    const float* __restrict__ x,
    const int* __restrict__ idx0_g, const int* __restrict__ idx1_g,
    const float* __restrict__ gn0_g, const float* __restrict__ gn1_g,
    const int* __restrict__ rank0_g, const int* __restrict__ rank1_g,
    const int* __restrict__ base_g, const int* __restrict__ tot0_g,
    float* __restrict__ out)
{
    const int s = blockIdx.x;
    const int chunk = s >> 6;
    const int e0 = idx0_g[s], e1 = idx1_g[s];
    const int loc0 = base_g[chunk * 64 + e0] + rank0_g[s];
    const int loc1 = base_g[(NCHUNK + chunk) * 64 + e1] + rank1_g[s] + tot0_g[e1];
    float w = 0.f;
    if (loc0 < CAPACITY) w += gn0_g[s];
    if (loc1 < CAPACITY) w += gn1_g[s];

    const float4* xr = (const float4*)(x + (size_t)s * M_DIM);
    float4* o = (float4*)(out + (size_t)s * M_DIM);
    #pragma unroll
    for (int i = 0; i < 4; ++i) {
        float4 v = xr[threadIdx.x + 256 * i];
        v.x *= w; v.y *= w; v.z *= w; v.w *= w;
        o[threadIdx.x + 256 * i] = v;
    }
}

// ---------------------------------------------------------------------------
extern "C" void kernel_launch(void* const* d_in, const int* in_sizes, int n_in,
                              void* d_out, int out_size, void* d_ws, size_t ws_size,
                              hipStream_t stream)
{
    const float* x  = (const float*)d_in[0];
    const float* wg = (const float*)d_in[1];
    float* out = (float*)d_out;
    float* loss = out + (size_t)S_TOK * M_DIM;

    // ws layout (floats/ints, 4B):
    float* part = (float*)d_ws;                         // [KS][S][E] = 33.55 MB
    float* me   = part + (size_t)KS * S_TOK * NEXP;     // [64]
    int*  idx0  = (int*)(me + NEXP);                    // [S]
    int*  idx1  = idx0 + S_TOK;                         // [S]
    float* gn0  = (float*)(idx1 + S_TOK);               // [S]
    float* gn1  = gn0 + S_TOK;                          // [S]
    int*  rank0 = (int*)(gn1 + S_TOK);                  // [S]
    int*  rank1 = rank0 + S_TOK;                        // [S]
    int*  cnt   = rank1 + S_TOK;                        // [2][128][64]
    int*  base  = cnt + 2 * NCHUNK * 64;                // [2][128][64]
    int*  tot0  = base + 2 * NCHUNK * 64;               // [64]

    hipMemsetAsync(me, 0, NEXP * sizeof(float), stream);
    hipMemsetAsync(loss, 0, sizeof(float), stream);

    k_logits<<<32 * KS, 256, 0, stream>>>(x, wg, part);
    k_gate<<<NCHUNK, 512, 0, stream>>>(part, me, idx0, idx1, gn0, gn1,
                                       rank0, rank1, cnt);
    k_scan<<<32, 256, 0, stream>>>(cnt, base, tot0, me, loss);
    k_out<<<S_TOK, 256, 0, stream>>>(x, idx0, idx1, gn0, gn1,
                                     rank0, rank1, base, tot0, out);
}